// Round 6
// baseline (146.230 us; speedup 1.0000x reference)
//
#include <hip/hip_runtime.h>

// ReceptiveFieldNorm, N=16 C=3 H=W=768, fp32. Two iterations (win 51 then 13
// at 256x256). 6 dispatches. This revision: 1024-thread blocks processing 4
// rows per barrier set (4x barrier amortization, 16 waves/CU) and LDS-staged
// vectorized subsample loads in k1.

#define N_B 16
#define CCH 3
#define HF 768
#define HL 256
#define SLICE (HL * HL)
#define TOT_L (N_B * SLICE)
#define EPSV 1e-3f

__device__ __forceinline__ int cnt(int i, int P) {
  int hi = i + P; if (hi > HL - 1) hi = HL - 1;
  int lo = i - P; if (lo < 0) lo = 0;
  return hi - lo + 1;
}

// Dual zero-padded horizontal box-sum; 4 independent rows (one per group g),
// each group = 4 contiguous waves scanning its own 256-wide row.
template <int P>
__device__ __forceinline__ void hbox2g(float a, float b, int g, int j,
    float (*s0)[HL], float (*s1)[HL], float (*wtA)[4], float (*wtB)[4],
    float& ra, float& rb) {
  int lane = j & 63, w = j >> 6;
  __syncthreads();  // protect LDS reuse across calls
#pragma unroll
  for (int d = 1; d < 64; d <<= 1) {
    float ta = __shfl_up(a, (unsigned)d);
    float tb = __shfl_up(b, (unsigned)d);
    if (lane >= d) { a += ta; b += tb; }
  }
  if (lane == 63) { wtA[g][w] = a; wtB[g][w] = b; }
  __syncthreads();
  float offa = 0.f, offb = 0.f;
  for (int ww = 0; ww < w; ++ww) { offa += wtA[g][ww]; offb += wtB[g][ww]; }
  s0[g][j] = a + offa;
  s1[g][j] = b + offb;
  __syncthreads();
  int hi = j + P; if (hi > HL - 1) hi = HL - 1;
  int lo = j - P - 1;
  ra = s0[g][hi]; rb = s1[g][hi];
  if (lo >= 0) { ra -= s0[g][lo]; rb -= s1[g][lo]; }
}

// ---------- k1: subsample + channel stats + h-scan(P=25); stores raw u,v.
// 1024 threads: 4 subsample rows per block, x-rows staged via float4 in LDS.
__global__ __launch_bounds__(1024) void k1(const float* __restrict__ x,
    float* __restrict__ u, float* __restrict__ v,
    float* __restrict__ t0, float* __restrict__ t1) {
  __shared__ float stage[4][HF];
  __shared__ float s0[4][HL], s1[4][HL];
  __shared__ float wtA[4][4], wtB[4][4];
  int b = blockIdx.x;
  int n = b >> 6;           // 64 blocks per image
  int ib = (b & 63) << 2;   // first of 4 subsample rows
  int tid = threadIdx.x;
  int g = tid >> 8, j = tid & 255;
  int srow = tid / 192, scol = (tid % 192) * 4;  // staging map (tid < 768)
  float ua = 0.f, va = 0.f;
  const size_t imgbase = (size_t)n * CCH * HF * HF;
  for (int c = 0; c < CCH; ++c) {
    __syncthreads();  // stage buffer reuse
    if (tid < 768) {
      const float* src = x + imgbase + (size_t)c * HF * HF
                       + (size_t)(3 * (ib + srow) + 1) * HF + scol;
      *(float4*)&stage[srow][scol] = *(const float4*)src;
    }
    __syncthreads();
    float val = stage[g][3 * j + 1];
    ua += val;
    va += val * val;
  }
  float uu = ua * (1.f / 3.f), vv = va * (1.f / 3.f);
  size_t base = ((size_t)(n * HL) + (ib + g)) * HL;
  u[base + j] = uu;
  v[base + j] = vv;
  float ra, rb;
  hbox2g<25>(uu, vv, g, j, s0, s1, wtA, wtB, ra, rb);
  t0[base + j] = ra;
  t1[base + j] = rb;
}

// ---------- vertical sliding-window box (radius P) + fused epilogue/h-scan(P2)
// 1024 threads, group g handles rows seg*16 + g + 4t (t=0..3); window slides by 4.
// MODE 0: -> a=1/std, b=-mean/std; h-scan P2 -> out
// MODE 2: -> A,B maps (m0,m1); iter-2 stats from u,v; h-scan P2 -> out
// MODE 1: -> A,B maps only
template <int P, int MODE, int P2>
__global__ __launch_bounds__(1024) void k_vs(const float* __restrict__ in0,
    const float* __restrict__ in1, float* __restrict__ out0,
    float* __restrict__ out1, const float* __restrict__ u,
    const float* __restrict__ v, float* __restrict__ m0,
    float* __restrict__ m1) {
  __shared__ float s0[4][HL], s1[4][HL];
  __shared__ float wtA[4][4], wtB[4][4];
  int n = blockIdx.x >> 4, seg = blockIdx.x & 15;
  int tid = threadIdx.x;
  int g = tid >> 8, j = tid & 255;
  const float* p0 = in0 + (size_t)n * SLICE;
  const float* p1 = in1 + (size_t)n * SLICE;
  int i = seg * 16 + g;
  float a0 = 0.f, a1 = 0.f;
  {
    int lo = i - P; if (lo < 0) lo = 0;
    int hi = i + P; if (hi > HL - 1) hi = HL - 1;
    for (int r = lo; r <= hi; ++r) { a0 += p0[r * HL + j]; a1 += p1[r * HL + j]; }
  }
  float cj = (float)cnt(j, P);
#pragma unroll
  for (int t = 0; t < 4; ++t) {
    float invM = 1.f / (cj * (float)cnt(i, P));
    size_t idx = (size_t)n * SLICE + (size_t)i * HL + j;
    float o0 = 0.f, o1 = 0.f;
    if constexpr (MODE == 0) {
      float xm = a0 * invM, x2m = a1 * invM;
      float var = x2m - xm * xm; if (var < 0.f) var = 0.f;
      float inv = 1.f / sqrtf(var + EPSV);
      o0 = inv; o1 = -xm * inv;
    } else {
      float A = a0 * invM, B = a1 * invM;
      m0[idx] = A; m1[idx] = B;
      if constexpr (MODE == 2) {
        float un = u[idx], vn = v[idx];
        o0 = A * un + B;
        o1 = A * A * vn + 2.f * A * B * un + B * B;
      }
    }
    if constexpr (MODE != 1) {
      float ra, rb;
      hbox2g<P2>(o0, o1, g, j, s0, s1, wtA, wtB, ra, rb);
      out0[idx] = ra;
      out1[idx] = rb;
    }
    if (t < 3) {
#pragma unroll
      for (int d = 1; d <= 4; ++d) {
        int ar = i + P + d;
        if (ar <= HL - 1) { a0 += p0[ar * HL + j]; a1 += p1[ar * HL + j]; }
        int sr = i - P + d - 1;
        if (sr >= 0) { a0 -= p0[sr * HL + j]; a1 -= p1[sr * HL + j]; }
      }
      i += 4;
    }
  }
}

// ---------- bilinear upsample weights for 256 -> 768 (period-3 pattern)
__device__ __forceinline__ void upw(int q, int& i0, int& i1, float& w1) {
  int d = q / 3;
  int r = q - 3 * d;
  if (r == 1) { i0 = d; i1 = d; w1 = 0.f; }
  else if (r == 2) { i0 = d; i1 = d + 1; if (i1 > HL - 1) i1 = HL - 1; w1 = 1.f / 3.f; }
  else { i1 = d; i0 = d - 1; if (i0 < 0) i0 = 0; w1 = 2.f / 3.f; }
}

// ---------- fused output: out = A2up * (A1up * x + B1up) + B2up
__global__ __launch_bounds__(192) void k_final(
    const float* __restrict__ x, const float* __restrict__ A1m,
    const float* __restrict__ B1m, const float* __restrict__ A2m,
    const float* __restrict__ B2m, float* __restrict__ out) {
  __shared__ float ry[4][HL];
  int nb = blockIdx.x;  // n*768 + y
  int y = nb % HF;
  int n = nb / HF;
  int t = threadIdx.x;
  int iy0, iy1;
  float wy1;
  upw(y, iy0, iy1, wy1);
  float wy0 = 1.f - wy1;
  size_t mb = (size_t)n * SLICE;
  for (int col = t; col < HL; col += 192) {
    ry[0][col] = wy0 * A1m[mb + (size_t)iy0 * HL + col] + wy1 * A1m[mb + (size_t)iy1 * HL + col];
    ry[1][col] = wy0 * B1m[mb + (size_t)iy0 * HL + col] + wy1 * B1m[mb + (size_t)iy1 * HL + col];
    ry[2][col] = wy0 * A2m[mb + (size_t)iy0 * HL + col] + wy1 * A2m[mb + (size_t)iy1 * HL + col];
    ry[3][col] = wy0 * B2m[mb + (size_t)iy0 * HL + col] + wy1 * B2m[mb + (size_t)iy1 * HL + col];
  }
  __syncthreads();
  float A1c[4], B1c[4], A2c[4], B2c[4];
#pragma unroll
  for (int e = 0; e < 4; ++e) {
    int q = 4 * t + e;
    int ix0, ix1;
    float wx1;
    upw(q, ix0, ix1, wx1);
    float wx0 = 1.f - wx1;
    A1c[e] = wx0 * ry[0][ix0] + wx1 * ry[0][ix1];
    B1c[e] = wx0 * ry[1][ix0] + wx1 * ry[1][ix1];
    A2c[e] = wx0 * ry[2][ix0] + wx1 * ry[2][ix1];
    B2c[e] = wx0 * ry[3][ix0] + wx1 * ry[3][ix1];
  }
  size_t rowbase = ((size_t)(n * CCH) * HF + y) * HF + 4 * t;
#pragma unroll
  for (int c = 0; c < CCH; ++c) {
    const float4 xin = *(const float4*)(x + rowbase + (size_t)c * HF * HF);
    float4 o;
    o.x = A2c[0] * (A1c[0] * xin.x + B1c[0]) + B2c[0];
    o.y = A2c[1] * (A1c[1] * xin.y + B1c[1]) + B2c[1];
    o.z = A2c[2] * (A1c[2] * xin.z + B1c[2]) + B2c[2];
    o.w = A2c[3] * (A1c[3] * xin.w + B1c[3]) + B2c[3];
    *(float4*)(out + rowbase + (size_t)c * HF * HF) = o;
  }
}

extern "C" void kernel_launch(void* const* d_in, const int* in_sizes, int n_in,
                              void* d_out, int out_size, void* d_ws, size_t ws_size,
                              hipStream_t stream) {
  const float* x = (const float*)d_in[0];
  float* out = (float*)d_out;
  const size_t S = (size_t)TOT_L;
  float* wsf = (float*)d_ws;
  float *u, *v, *t0, *t1, *t2, *t3, *A1, *B1, *A2, *B2;
  if (ws_size >= 10 * S * sizeof(float)) {
    u = wsf;      v = u + S;   t0 = v + S;   t1 = t0 + S;  t2 = t1 + S;
    t3 = t2 + S;  A1 = t3 + S; B1 = A1 + S;  A2 = B1 + S;  B2 = A2 + S;
  } else {
    // Maps k_final reads stay in ws (16 MB); transients live at the head of
    // d_out (each fully written before read, every call).
    A1 = wsf; B1 = A1 + S; A2 = B1 + S; B2 = A2 + S;
    u = out; v = u + S; t0 = v + S; t1 = t0 + S; t2 = t1 + S; t3 = t2 + S;
  }

  k1<<<N_B * 64, 1024, 0, stream>>>(x, u, v, t0, t1);
  k_vs<25, 0, 25><<<N_B * 16, 1024, 0, stream>>>(t0, t1, t2, t3, nullptr, nullptr, nullptr, nullptr);
  k_vs<25, 2, 6><<<N_B * 16, 1024, 0, stream>>>(t2, t3, t0, t1, u, v, A1, B1);
  k_vs<6, 0, 6><<<N_B * 16, 1024, 0, stream>>>(t0, t1, t2, t3, nullptr, nullptr, nullptr, nullptr);
  k_vs<6, 1, 0><<<N_B * 16, 1024, 0, stream>>>(t2, t3, nullptr, nullptr, nullptr, nullptr, A2, B2);
  k_final<<<N_B * HF, 192, 0, stream>>>(x, A1, B1, A2, B2, out);
}